// Round 7
// baseline (603.415 us; speedup 1.0000x reference)
//
#include <hip/hip_runtime.h>

// EMA Vector-Quantizer for MI355X (gfx950).
// N=16384 tokens, D=64, K=8192. Dominant cost: 16384x8192x64 fp32 GEMM for
// distance argmin (no fp32 MFMA on CDNA4 -> VALU, 109 us FMA-issue floor).
// Structure (proven R4): z tile in LDS (broadcast reads), w from pre-transposed
// w_t[d][k] in global (L2/L1-resident, contiguous dwordx4), single barrier.
// R7 fix: allocator picks arch-VGPR budget from the LDS-implied occupancy cap
// (R2-R5 evidence: LDS<=32KB -> 5 blocks/CU target -> 102-VGPR budget ->
// quantizes to 64 -> acc[8][8] shuttled to AGPRs (R4, 3x issue) or scratch
// (R3/R5, 140MB spill)). A 28KB dummy pad forces 2 blocks/CU -> 256-VGPR
// budget -> acc stays in arch VGPRs (R1/R2 precedent: 88-120 granted).
// GROUPS=4 -> 512 blocks = exactly 2/CU, single dispatch pass.

#define N_TOK 16384
#define K_EMB 8192
#define EMB_D 64
#define TN 128
#define GROUPS 4
#define KPG (K_EMB / GROUPS)   // 2048 codes per k-group, 16 kb-tiles of 128

// d_out flat layout (float32), in reference return order:
// z_q (1048576) | loss | new_weight (524288) | new_cluster_size (8192) | new_embed_avg (524288)
#define OFF_LOSS 1048576
#define OFF_W    1048577
#define OFF_CS   1572865
#define OFF_EA   1581057

// scratch inside the z_q region of out (all < 1048576, overwritten by k_quant)
#define OUT_WT 0                        // w_t[d][k]: 64 x 8192 = 524288 floats
#define OUT_CD 524288                   // cand dist [GROUPS][N_TOK] = 65536
#define OUT_CI (524288 + 65536)         // cand idx  [GROUPS][N_TOK] = 65536

// ws float offsets
#define WS_NSUM  0
#define WS_LOSS  1
#define WS_WNORM 16
#define WS_IDX   (WS_WNORM + K_EMB)

// ---------------------------------------------------------------------------
// K0: wnorm[k]; transpose weight -> w_t[d][k] (in out); zero accumulators.
__global__ void k_prep(const float* __restrict__ weight,
                       float* __restrict__ out, float* __restrict__ ws) {
  int gid = blockIdx.x * 256 + threadIdx.x;     // 0..131071
  int row = gid >> 4;                            // codebook row 0..8191
  int l16 = gid & 15;
  float4 w4 = *(const float4*)(weight + row * EMB_D + l16 * 4);
  float s = w4.x * w4.x + w4.y * w4.y + w4.z * w4.z + w4.w * w4.w;
  #pragma unroll
  for (int off = 8; off > 0; off >>= 1) s += __shfl_xor(s, off, 16);
  if (l16 == 0) ws[WS_WNORM + row] = s;

  // transposed copy: w_t[d*8192 + row], d = l16*4+c
  out[OUT_WT + (l16 * 4 + 0) * K_EMB + row] = w4.x;
  out[OUT_WT + (l16 * 4 + 1) * K_EMB + row] = w4.y;
  out[OUT_WT + (l16 * 4 + 2) * K_EMB + row] = w4.z;
  out[OUT_WT + (l16 * 4 + 3) * K_EMB + row] = w4.w;

  #pragma unroll
  for (int j = 0; j < 4; ++j) out[OFF_EA + gid * 4 + j] = 0.f;
  if (gid < K_EMB) out[OFF_CS + gid] = 0.f;
  if (gid == 0) { out[OFF_LOSS] = 0.f; ws[WS_NSUM] = 0.f; ws[WS_LOSS] = 0.f; }
}

// ---------------------------------------------------------------------------
// K1: distance argmin. Block: 128 n x 2048 k; thread tile 8n x 8k.
// grid (128, 4) x 256 threads = 512 blocks = exactly 2/CU (60KB LDS cap).
// w fragment: k = ktb + g*64 + tx*4 + j -> contiguous dwordx4 from w_t rows.
// z fragment: LDS broadcast (4 distinct addresses per wave-read, conflict-free).
__global__ __launch_bounds__(256, 2) void k_argmin(
    const float* __restrict__ z, const float* __restrict__ wt,
    const float* __restrict__ wnorm, float* __restrict__ cd,
    int* __restrict__ ci) {
  __shared__ __align__(16) float z_s[EMB_D * TN];  // [d][n], 32 KB
  // Occupancy pin: +28KB -> 60KB total -> 2 blocks/CU -> 256-VGPR budget so
  // acc[8][8] stays in arch VGPRs (no AGPR shuttle / scratch spill). The
  // guard can never be true at runtime; compiler can't prove it, pad stays.
  __shared__ float occ_pad[7168];
  const int t = threadIdx.x;
  const int n0 = blockIdx.x * TN;
  if (n0 > (1 << 28)) occ_pad[t] = 0.f;
  const int kbase = blockIdx.y * KPG;
  // z is (b, c, hw): z_flat[n][d] = z[b*65536 + d*1024 + hw], n = b*1024+hw.
  const float* zb = z + ((n0 >> 10) << 16) + (n0 & 1023);

  #pragma unroll
  for (int i = 0; i < 8; ++i) {
    int f4 = i * 256 + t;                 // 0..2047 float4s
    int d = f4 >> 5, c4 = (f4 & 31) * 4;
    *(float4*)(z_s + d * TN + c4) = *(const float4*)(zb + d * 1024 + c4);
  }
  __syncthreads();                        // the only barrier

  const int tx = t & 15, ty = t >> 4;     // tx -> k, ty -> n
  float bestd[8];
  int besti[8];
  #pragma unroll
  for (int i = 0; i < 8; ++i) { bestd[i] = 3.4e38f; besti[i] = 0; }

  for (int kb = 0; kb < KPG / 128; ++kb) {
    const int ktb = kbase + kb * 128;
    float4 wn0 = *(const float4*)(wnorm + ktb + tx * 4);
    float4 wn1 = *(const float4*)(wnorm + ktb + 64 + tx * 4);

    float acc[8][8];
    #pragma unroll
    for (int i = 0; i < 8; ++i)
      #pragma unroll
      for (int j = 0; j < 8; ++j) acc[i][j] = 0.f;

    const float* wp = wt + ktb + tx * 4;  // row stride K_EMB per d
    #pragma unroll 4
    for (int d = 0; d < EMB_D; ++d) {
      float4 z0 = *(const float4*)(z_s + d * TN + ty * 8);
      float4 z1 = *(const float4*)(z_s + d * TN + ty * 8 + 4);
      float4 w0 = *(const float4*)(wp);
      float4 w1 = *(const float4*)(wp + 64);
      wp += K_EMB;
      float zr[8] = {z0.x, z0.y, z0.z, z0.w, z1.x, z1.y, z1.z, z1.w};
      float wr[8] = {w0.x, w0.y, w0.z, w0.w, w1.x, w1.y, w1.z, w1.w};
      #pragma unroll
      for (int i = 0; i < 8; ++i)
        #pragma unroll
        for (int j = 0; j < 8; ++j)
          acc[i][j] = fmaf(zr[i], wr[j], acc[i][j]);
    }

    // dist = |w|^2 - 2*dot. Per-thread k ascends over (g, j) -> strict <
    // keeps first-min; cross-thread ties resolved by index compare below.
    float wna[8] = {wn0.x, wn0.y, wn0.z, wn0.w, wn1.x, wn1.y, wn1.z, wn1.w};
    #pragma unroll
    for (int g = 0; g < 2; ++g)
      #pragma unroll
      for (int j = 0; j < 4; ++j) {
        int col = g * 4 + j;
        int kg = ktb + g * 64 + tx * 4 + j;
        float wn = wna[col];
        #pragma unroll
        for (int i = 0; i < 8; ++i) {
          float dist = fmaf(-2.f, acc[i][col], wn);
          if (dist < bestd[i]) { bestd[i] = dist; besti[i] = kg; }
        }
      }
  }

  // Reduce across the 16 tx threads sharing each n (same wave, width 16).
  #pragma unroll
  for (int i = 0; i < 8; ++i) {
    float bd = bestd[i]; int bi = besti[i];
    #pragma unroll
    for (int off = 8; off > 0; off >>= 1) {
      float od = __shfl_xor(bd, off, 16);
      int oi = __shfl_xor(bi, off, 16);
      if (od < bd || (od == bd && oi < bi)) { bd = od; bi = oi; }
    }
    if (tx == 0) {
      int n = n0 + ty * 8 + i;
      cd[blockIdx.y * N_TOK + n] = bd;
      ci[blockIdx.y * N_TOK + n] = bi;
    }
  }
}

// ---------------------------------------------------------------------------
// K2: reduce the GROUPS candidates per token; enc_sum atomics.
// Groups cover ascending k-ranges, so strict < keeps smallest index on tie.
__global__ void k_reduce(const float* __restrict__ cd, const int* __restrict__ ci,
                         int* __restrict__ idx, float* __restrict__ enc) {
  int n = blockIdx.x * 256 + threadIdx.x;
  float bd = cd[n]; int bi = ci[n];
  #pragma unroll
  for (int g = 1; g < GROUPS; ++g) {
    float od = cd[g * N_TOK + n];
    int oi = ci[g * N_TOK + n];
    if (od < bd) { bd = od; bi = oi; }
  }
  idx[n] = bi;
  atomicAdd(enc + bi, 1.0f);
}

// ---------------------------------------------------------------------------
// K3: z_q gather + straight-through output + loss partials + embed_sum atomics.
__global__ void k_quant(const float* __restrict__ z, const float* __restrict__ weight,
                        const int* __restrict__ idx, float* __restrict__ out,
                        float* __restrict__ embed_acc, float* __restrict__ ws) {
  int base = blockIdx.x * 1024 + threadIdx.x;
  float lsum = 0.f;
  #pragma unroll
  for (int i = 0; i < 4; ++i) {
    int e = base + i * 256;               // (b,c,hw) flat, same layout as z
    int c = (e >> 10) & 63;
    int n = ((e >> 16) << 10) | (e & 1023);
    int k = idx[n];
    float zv = z[e];
    float q = weight[k * EMB_D + c];
    out[e] = zv + (q - zv);               // straight-through value
    float d = q - zv;
    lsum += d * d;
    atomicAdd(embed_acc + k * EMB_D + c, zv);
  }
  #pragma unroll
  for (int off = 32; off > 0; off >>= 1) lsum += __shfl_xor(lsum, off, 64);
  __shared__ float red[4];
  int lane = threadIdx.x & 63, wv = threadIdx.x >> 6;
  if (lane == 0) red[wv] = lsum;
  __syncthreads();
  if (threadIdx.x == 0)
    atomicAdd(ws + WS_LOSS, red[0] + red[1] + red[2] + red[3]);
}

// ---------------------------------------------------------------------------
// K4: new_cluster_size (in place over enc_sum), n-sum, loss finalize.
__global__ void k_cluster(const float* __restrict__ cluster_in,
                          float* __restrict__ out, float* __restrict__ ws) {
  int k = blockIdx.x * 256 + threadIdx.x;
  float ncs = cluster_in[k] * 0.99f + 0.01f * out[OFF_CS + k];
  out[OFF_CS + k] = ncs;
  float s = ncs;
  #pragma unroll
  for (int off = 32; off > 0; off >>= 1) s += __shfl_xor(s, off, 64);
  __shared__ float red[4];
  int lane = threadIdx.x & 63, wv = threadIdx.x >> 6;
  if (lane == 0) red[wv] = s;
  __syncthreads();
  if (threadIdx.x == 0) atomicAdd(ws + WS_NSUM, red[0] + red[1] + red[2] + red[3]);
  if (blockIdx.x == 0 && threadIdx.x == 0)
    out[OFF_LOSS] = 0.25f * ws[WS_LOSS] * (1.0f / 1048576.0f);
}

// ---------------------------------------------------------------------------
// K5: smoothed cluster sizes -> new_weight; new_embed_avg (in place).
__global__ void k_final(const float* __restrict__ embed_avg,
                        float* __restrict__ out, const float* __restrict__ ws) {
  int e = blockIdx.x * 256 + threadIdx.x;   // < 524288
  int k = e >> 6;
  float ncs = out[OFF_CS + k];
  float nsum = ws[WS_NSUM];
  float sm = (ncs + 1e-5f) / (nsum + K_EMB * 1e-5f) * nsum;
  float ea = embed_avg[e] * 0.99f + 0.01f * out[OFF_EA + e];
  out[OFF_EA + e] = ea;
  out[OFF_W + e] = ea / sm;
}

// ---------------------------------------------------------------------------
extern "C" void kernel_launch(void* const* d_in, const int* in_sizes, int n_in,
                              void* d_out, int out_size, void* d_ws, size_t ws_size,
                              hipStream_t stream) {
  const float* z = (const float*)d_in[0];
  const float* weight = (const float*)d_in[1];
  const float* cluster = (const float*)d_in[2];
  const float* embed_avg = (const float*)d_in[3];
  float* out = (float*)d_out;
  float* ws = (float*)d_ws;
  float* wnorm = ws + WS_WNORM;
  int* idx = (int*)(ws + WS_IDX);
  float* wt = out + OUT_WT;               // scratch in z_q region
  float* cd = out + OUT_CD;
  int* ci = (int*)(out + OUT_CI);

  hipLaunchKernelGGL(k_prep, dim3(512), dim3(256), 0, stream, weight, out, ws);
  hipLaunchKernelGGL(k_argmin, dim3(N_TOK / TN, GROUPS), dim3(256), 0, stream,
                     z, wt, wnorm, cd, ci);
  hipLaunchKernelGGL(k_reduce, dim3(N_TOK / 256), dim3(256), 0, stream,
                     cd, ci, idx, out + OFF_CS);
  hipLaunchKernelGGL(k_quant, dim3(1024), dim3(256), 0, stream,
                     z, weight, idx, out, out + OFF_EA, ws);
  hipLaunchKernelGGL(k_cluster, dim3(K_EMB / 256), dim3(256), 0, stream,
                     cluster, out, ws);
  hipLaunchKernelGGL(k_final, dim3(524288 / 256), dim3(256), 0, stream,
                     embed_avg, out, ws);
}

// Round 8
// 454.462 us; speedup vs baseline: 1.3278x; 1.3278x over previous
//
#include <hip/hip_runtime.h>

// EMA Vector-Quantizer for MI355X (gfx950).
// N=16384 tokens, D=64, K=8192. Dominant cost: 16384x8192x64 fp32 GEMM for
// distance argmin (no fp32 MFMA on CDNA4 -> VALU, 109 us FMA-issue floor).
// Structure (R4, proven): z tile in LDS (broadcast reads), w from
// pre-transposed w_t[d][k] in global (L1/L2-resident contiguous dwordx4),
// single barrier, GROUPS=8 -> 1024 blocks.
// Allocator model (R2-R7): arch-VGPR budget = 512 / (LDS-implied blocks/CU
// target). LDS<=32KB -> target 5 -> budget 102 -> quantize 64 -> acc[8][8]
// goes to AGPRs (v_accvgpr shuttles, 3x issue) or scratch (140MB spills).
// LDS ~60KB -> target 2 -> budget 256 -> acc stays in arch VGPRs (R1/R2:
// 88-120 granted). R7's plain dummy pad was DCE'd (dead store -> array
// removed -> LDS back to 32KB). R8: volatile pad whose value flows into a
// conditional global store the compiler cannot prove dead.

#define N_TOK 16384
#define K_EMB 8192
#define EMB_D 64
#define TN 128
#define GROUPS 8
#define KPG (K_EMB / GROUPS)   // 1024 codes per k-group, 8 kb-tiles of 128

// d_out flat layout (float32), in reference return order:
// z_q (1048576) | loss | new_weight (524288) | new_cluster_size (8192) | new_embed_avg (524288)
#define OFF_LOSS 1048576
#define OFF_W    1048577
#define OFF_CS   1572865
#define OFF_EA   1581057

// scratch inside the z_q region of out (all < 1048576, overwritten by k_quant)
#define OUT_WT 0                        // w_t[d][k]: 64 x 8192 = 524288 floats
#define OUT_CD 524288                   // cand dist [GROUPS][N_TOK] = 131072
#define OUT_CI (524288 + 131072)        // cand idx  [GROUPS][N_TOK] = 131072

// ws float offsets
#define WS_NSUM  0
#define WS_LOSS  1
#define WS_WNORM 16
#define WS_IDX   (WS_WNORM + K_EMB)

// ---------------------------------------------------------------------------
// K0: wnorm[k]; transpose weight -> w_t[d][k] (in out); zero accumulators.
__global__ void k_prep(const float* __restrict__ weight,
                       float* __restrict__ out, float* __restrict__ ws) {
  int gid = blockIdx.x * 256 + threadIdx.x;     // 0..131071
  int row = gid >> 4;                            // codebook row 0..8191
  int l16 = gid & 15;
  float4 w4 = *(const float4*)(weight + row * EMB_D + l16 * 4);
  float s = w4.x * w4.x + w4.y * w4.y + w4.z * w4.z + w4.w * w4.w;
  #pragma unroll
  for (int off = 8; off > 0; off >>= 1) s += __shfl_xor(s, off, 16);
  if (l16 == 0) ws[WS_WNORM + row] = s;

  // transposed copy: w_t[d*8192 + row], d = l16*4+c
  out[OUT_WT + (l16 * 4 + 0) * K_EMB + row] = w4.x;
  out[OUT_WT + (l16 * 4 + 1) * K_EMB + row] = w4.y;
  out[OUT_WT + (l16 * 4 + 2) * K_EMB + row] = w4.z;
  out[OUT_WT + (l16 * 4 + 3) * K_EMB + row] = w4.w;

  #pragma unroll
  for (int j = 0; j < 4; ++j) out[OFF_EA + gid * 4 + j] = 0.f;
  if (gid < K_EMB) out[OFF_CS + gid] = 0.f;
  if (gid == 0) { out[OFF_LOSS] = 0.f; ws[WS_NSUM] = 0.f; ws[WS_LOSS] = 0.f; }
}

// ---------------------------------------------------------------------------
// K1: distance argmin. Block: 128 n x 1024 k; thread tile 8n x 8k.
// grid (128, 8) x 256 threads; 60KB LDS -> 2 blocks/CU -> 256-VGPR budget.
// w fragment: k = ktb + g*64 + tx*4 + j -> contiguous dwordx4 from w_t rows.
// z fragment: LDS broadcast (4 distinct addresses per wave-read, conflict-free).
__global__ __launch_bounds__(256, 2) void k_argmin(
    const float* __restrict__ z, const float* __restrict__ wt,
    const float* __restrict__ wnorm, float* __restrict__ cd,
    int* __restrict__ ci) {
  __shared__ __align__(16) float z_s[EMB_D * TN];  // [d][n], 32 KB
  // Occupancy pin (28 KB -> 60 KB total). volatile + value escaping to a
  // global store under a branch the compiler cannot prove dead (blockIdx.y
  // is unbounded at compile time) -> the array cannot be eliminated.
  volatile __shared__ float occ_pad[7168];
  const int t = threadIdx.x;
  const int n0 = blockIdx.x * TN;
  const int kbase = blockIdx.y * KPG;
  if (kbase > (1 << 28)) {                // never true at runtime (kbase<8192)
    occ_pad[t] = wnorm[t];
    cd[t] = occ_pad[t ^ 1];
  }
  // z is (b, c, hw): z_flat[n][d] = z[b*65536 + d*1024 + hw], n = b*1024+hw.
  const float* zb = z + ((n0 >> 10) << 16) + (n0 & 1023);

  #pragma unroll
  for (int i = 0; i < 8; ++i) {
    int f4 = i * 256 + t;                 // 0..2047 float4s
    int d = f4 >> 5, c4 = (f4 & 31) * 4;
    *(float4*)(z_s + d * TN + c4) = *(const float4*)(zb + d * 1024 + c4);
  }
  __syncthreads();                        // the only barrier

  const int tx = t & 15, ty = t >> 4;     // tx -> k, ty -> n
  float bestd[8];
  int besti[8];
  #pragma unroll
  for (int i = 0; i < 8; ++i) { bestd[i] = 3.4e38f; besti[i] = 0; }

  for (int kb = 0; kb < KPG / 128; ++kb) {
    const int ktb = kbase + kb * 128;
    float4 wn0 = *(const float4*)(wnorm + ktb + tx * 4);
    float4 wn1 = *(const float4*)(wnorm + ktb + 64 + tx * 4);

    float acc[8][8];
    #pragma unroll
    for (int i = 0; i < 8; ++i)
      #pragma unroll
      for (int j = 0; j < 8; ++j) acc[i][j] = 0.f;

    const float* wp = wt + ktb + tx * 4;  // row stride K_EMB per d
    #pragma unroll 4
    for (int d = 0; d < EMB_D; ++d) {
      float4 z0 = *(const float4*)(z_s + d * TN + ty * 8);
      float4 z1 = *(const float4*)(z_s + d * TN + ty * 8 + 4);
      float4 w0 = *(const float4*)(wp);
      float4 w1 = *(const float4*)(wp + 64);
      wp += K_EMB;
      float zr[8] = {z0.x, z0.y, z0.z, z0.w, z1.x, z1.y, z1.z, z1.w};
      float wr[8] = {w0.x, w0.y, w0.z, w0.w, w1.x, w1.y, w1.z, w1.w};
      #pragma unroll
      for (int i = 0; i < 8; ++i)
        #pragma unroll
        for (int j = 0; j < 8; ++j)
          acc[i][j] = fmaf(zr[i], wr[j], acc[i][j]);
    }

    // dist = |w|^2 - 2*dot. Per-thread k ascends over (g, j) -> strict <
    // keeps first-min; cross-thread ties resolved by index compare below.
    float wna[8] = {wn0.x, wn0.y, wn0.z, wn0.w, wn1.x, wn1.y, wn1.z, wn1.w};
    #pragma unroll
    for (int g = 0; g < 2; ++g)
      #pragma unroll
      for (int j = 0; j < 4; ++j) {
        int col = g * 4 + j;
        int kg = ktb + g * 64 + tx * 4 + j;
        float wn = wna[col];
        #pragma unroll
        for (int i = 0; i < 8; ++i) {
          float dist = fmaf(-2.f, acc[i][col], wn);
          if (dist < bestd[i]) { bestd[i] = dist; besti[i] = kg; }
        }
      }
  }

  // Reduce across the 16 tx threads sharing each n (same wave, width 16).
  #pragma unroll
  for (int i = 0; i < 8; ++i) {
    float bd = bestd[i]; int bi = besti[i];
    #pragma unroll
    for (int off = 8; off > 0; off >>= 1) {
      float od = __shfl_xor(bd, off, 16);
      int oi = __shfl_xor(bi, off, 16);
      if (od < bd || (od == bd && oi < bi)) { bd = od; bi = oi; }
    }
    if (tx == 0) {
      int n = n0 + ty * 8 + i;
      cd[blockIdx.y * N_TOK + n] = bd;
      ci[blockIdx.y * N_TOK + n] = bi;
    }
  }
}

// ---------------------------------------------------------------------------
// K2: reduce the GROUPS candidates per token; enc_sum atomics.
// Groups cover ascending k-ranges, so strict < keeps smallest index on tie.
__global__ void k_reduce(const float* __restrict__ cd, const int* __restrict__ ci,
                         int* __restrict__ idx, float* __restrict__ enc) {
  int n = blockIdx.x * 256 + threadIdx.x;
  float bd = cd[n]; int bi = ci[n];
  #pragma unroll
  for (int g = 1; g < GROUPS; ++g) {
    float od = cd[g * N_TOK + n];
    int oi = ci[g * N_TOK + n];
    if (od < bd) { bd = od; bi = oi; }
  }
  idx[n] = bi;
  atomicAdd(enc + bi, 1.0f);
}

// ---------------------------------------------------------------------------
// K3: z_q gather + straight-through output + loss partials + embed_sum atomics.
__global__ void k_quant(const float* __restrict__ z, const float* __restrict__ weight,
                        const int* __restrict__ idx, float* __restrict__ out,
                        float* __restrict__ embed_acc, float* __restrict__ ws) {
  int base = blockIdx.x * 1024 + threadIdx.x;
  float lsum = 0.f;
  #pragma unroll
  for (int i = 0; i < 4; ++i) {
    int e = base + i * 256;               // (b,c,hw) flat, same layout as z
    int c = (e >> 10) & 63;
    int n = ((e >> 16) << 10) | (e & 1023);
    int k = idx[n];
    float zv = z[e];
    float q = weight[k * EMB_D + c];
    out[e] = zv + (q - zv);               // straight-through value
    float d = q - zv;
    lsum += d * d;
    atomicAdd(embed_acc + k * EMB_D + c, zv);
  }
  #pragma unroll
  for (int off = 32; off > 0; off >>= 1) lsum += __shfl_xor(lsum, off, 64);
  __shared__ float red[4];
  int lane = threadIdx.x & 63, wv = threadIdx.x >> 6;
  if (lane == 0) red[wv] = lsum;
  __syncthreads();
  if (threadIdx.x == 0)
    atomicAdd(ws + WS_LOSS, red[0] + red[1] + red[2] + red[3]);
}

// ---------------------------------------------------------------------------
// K4: new_cluster_size (in place over enc_sum), n-sum, loss finalize.
__global__ void k_cluster(const float* __restrict__ cluster_in,
                          float* __restrict__ out, float* __restrict__ ws) {
  int k = blockIdx.x * 256 + threadIdx.x;
  float ncs = cluster_in[k] * 0.99f + 0.01f * out[OFF_CS + k];
  out[OFF_CS + k] = ncs;
  float s = ncs;
  #pragma unroll
  for (int off = 32; off > 0; off >>= 1) s += __shfl_xor(s, off, 64);
  __shared__ float red[4];
  int lane = threadIdx.x & 63, wv = threadIdx.x >> 6;
  if (lane == 0) red[wv] = s;
  __syncthreads();
  if (threadIdx.x == 0) atomicAdd(ws + WS_NSUM, red[0] + red[1] + red[2] + red[3]);
  if (blockIdx.x == 0 && threadIdx.x == 0)
    out[OFF_LOSS] = 0.25f * ws[WS_LOSS] * (1.0f / 1048576.0f);
}

// ---------------------------------------------------------------------------
// K5: smoothed cluster sizes -> new_weight; new_embed_avg (in place).
__global__ void k_final(const float* __restrict__ embed_avg,
                        float* __restrict__ out, const float* __restrict__ ws) {
  int e = blockIdx.x * 256 + threadIdx.x;   // < 524288
  int k = e >> 6;
  float ncs = out[OFF_CS + k];
  float nsum = ws[WS_NSUM];
  float sm = (ncs + 1e-5f) / (nsum + K_EMB * 1e-5f) * nsum;
  float ea = embed_avg[e] * 0.99f + 0.01f * out[OFF_EA + e];
  out[OFF_EA + e] = ea;
  out[OFF_W + e] = ea / sm;
}

// ---------------------------------------------------------------------------
extern "C" void kernel_launch(void* const* d_in, const int* in_sizes, int n_in,
                              void* d_out, int out_size, void* d_ws, size_t ws_size,
                              hipStream_t stream) {
  const float* z = (const float*)d_in[0];
  const float* weight = (const float*)d_in[1];
  const float* cluster = (const float*)d_in[2];
  const float* embed_avg = (const float*)d_in[3];
  float* out = (float*)d_out;
  float* ws = (float*)d_ws;
  float* wnorm = ws + WS_WNORM;
  int* idx = (int*)(ws + WS_IDX);
  float* wt = out + OUT_WT;               // scratch in z_q region
  float* cd = out + OUT_CD;
  int* ci = (int*)(out + OUT_CI);

  hipLaunchKernelGGL(k_prep, dim3(512), dim3(256), 0, stream, weight, out, ws);
  hipLaunchKernelGGL(k_argmin, dim3(N_TOK / TN, GROUPS), dim3(256), 0, stream,
                     z, wt, wnorm, cd, ci);
  hipLaunchKernelGGL(k_reduce, dim3(N_TOK / 256), dim3(256), 0, stream,
                     cd, ci, idx, out + OFF_CS);
  hipLaunchKernelGGL(k_quant, dim3(1024), dim3(256), 0, stream,
                     z, weight, idx, out, out + OFF_EA, ws);
  hipLaunchKernelGGL(k_cluster, dim3(K_EMB / 256), dim3(256), 0, stream,
                     cluster, out, ws);
  hipLaunchKernelGGL(k_final, dim3(524288 / 256), dim3(256), 0, stream,
                     embed_avg, out, ws);
}